// Round 9
// baseline (373.669 us; speedup 1.0000x reference)
//
#include <hip/hip_runtime.h>
#include <math.h>

#define BB 256
#define CC 500
#define LL 200
#define DD 64
#define HH 128
#define NUM_ITEMS 100000
#define BETA 0.7f
#define EPSV 1e-8f

#define TM 32                        // items per tile (per mlp block)
#define NTILE (NUM_ITEMS / TM)       // 3125 exactly
#define BPS 1024                     // mlp blocks per weight set
#define NB_MLP (2 * BPS)             // 2048 mlp-role blocks
#define NB_HWK 512                   // persistent hawkes-role blocks
#define NB_ALL (NB_MLP + NB_HWK)     // 2560; bid%5==4 -> hawkes
#define NROW (BB * CC)               // 128000 rows; 250 rows per hawkes block

typedef _Float16 half8 __attribute__((ext_vector_type(8)));
typedef _Float16 half4 __attribute__((ext_vector_type(4)));
typedef __fp16   pk2   __attribute__((ext_vector_type(2)));  // cvt_pkrtz result type
typedef float floatx4 __attribute__((ext_vector_type(4)));

// Safe softplus (final scalar, any range)
__device__ __forceinline__ float softplus_safe(float x) {
    float t = __expf(-fabsf(x));
    return fmaxf(x, 0.0f) + __logf(1.0f + t);
}
// Layer-2 softplus: |x| bounded (~+-6 typical); exact fp32 form.
__device__ __forceinline__ float softplus_fast(float x) {
    return __logf(1.0f + __expf(x));
}
// Layer-1 softplus: preacts tiny (sigma~0.016). Taylor deg-4, err < f16 rounding.
__device__ __forceinline__ float softplus_small(float x) {
    float z = x * x;
    float p = fmaf(fmaf(-5.2083333e-3f, z, 0.125f), z, 0.69314718f);
    return fmaf(x, 0.5f, p);
}

// Duration-matched role-split fused kernel (fix of r6's zero-overlap failure).
//  - bid%5==4 (512 blocks): PERSISTENT hawkes role — each block owns a
//    contiguous 250-row window, each wave ~62 rows (~25-30us lifetime,
//    matching mlp block duration), so every CU keeps an HBM-streaming
//    role and a VALU/MFMA role resident for the whole kernel.
//    Writes spart[r] only (no ma2 dependency -> true concurrency).
//  - Other 2048 blocks: the r3/r7-verified transposed-MFMA MLP body
//    (one weight set per block, 2 barriers/tile), writing interleaved
//    ma2[2*item+set].
// launch_bounds(256,8): VGPR=64 measured in r6/r7 -> 8 blocks/CU fits
// without spill; doubles resident waves for both roles.
__global__ __launch_bounds__(256, 8) void fused(
    const float* __restrict__ emb,
    const float* __restrict__ W1, const float* __restrict__ b1,
    const float* __restrict__ W2, const float* __restrict__ b2,
    const float* __restrict__ W3,
    const float* __restrict__ V1, const float* __restrict__ c1,
    const float* __restrict__ V2, const float* __restrict__ c2,
    const float* __restrict__ V3,
    const float* __restrict__ qt,
    const float* __restrict__ hist,
    float* __restrict__ ma2,          // [NUM_ITEMS][2] interleaved mu,alpha
    float* __restrict__ spart)        // [NROW] scaled history sums
{
    __shared__ __align__(16) _Float16 h1s[TM * HH];   // 8192 B
    __shared__ __align__(16) float    part[TM * 4];   // 512 B
    int bid  = blockIdx.x;
    int tid  = threadIdx.x;
    int w    = tid >> 6, lane = tid & 63;

    if (bid % 5 == 4) {
        // ---------------- persistent hawkes role ----------------
        int hslot = bid / 5;                  // 0..NB_HWK-1
        int rend  = hslot * 250 + 250;        // 512*250 = 128000 exact
        #pragma unroll 2
        for (int r = hslot * 250 + w; r < rend; r += 4) {
            float q = qt[r / CC];
            float s = 0.0f;
            if (lane < LL / 4) {
                const floatx4* hp = (const floatx4*)(hist + (size_t)r * LL) + lane;
                floatx4 v = *hp;
                s  = (v[0] < q) ? __expf(BETA * v[0]) : 0.f;
                s += (v[1] < q) ? __expf(BETA * v[1]) : 0.f;
                s += (v[2] < q) ? __expf(BETA * v[2]) : 0.f;
                s += (v[3] < q) ? __expf(BETA * v[3]) : 0.f;
            }
            #pragma unroll
            for (int off = 1; off < 64; off <<= 1) s += __shfl_xor(s, off, 64);
            if (lane == 0)
                spart[r] = s * __expf(-BETA * q);
        }
        return;
    }

    // ---------------- mlp role (r3/r7-verified body) ----------------
    int mslot = bid - bid / 5;                // dense 0..NB_MLP-1 over bid%5!=4
    int quad = lane >> 4, l15 = lane & 15;

    int is_exc = mslot >= BPS;                // block-uniform
    int bslot  = mslot - (is_exc ? BPS : 0);  // 0..BPS-1

    const float* W1s = is_exc ? V1 : W1;
    const float* W2s = is_exc ? V2 : W2;
    const float* B1s = is_exc ? c1 : b1;
    const float* B2s = is_exc ? c2 : b2;
    const float* W3s = is_exc ? V3 : W3;

    // ---- stationary weights: wave w owns col groups 2w, 2w+1 ----
    half8 w1f[2][2];   // [kt][n]  (A-operand = W1^T slice)
    half8 w2f[4][2];   // [kt][n]  (A-operand = W2^T slice)
    floatx4 b1v[2], b2v[2], w3v[2];   // component r = col (2w+n)*16+quad*4+r
    #pragma unroll
    for (int n = 0; n < 2; ++n) {
        int j  = (2 * w + n) * 16 + l15;        // A-frag lane col
        int cb = (2 * w + n) * 16 + quad * 4;   // transposed-output col base
        #pragma unroll
        for (int r = 0; r < 4; ++r) {
            b1v[n][r] = B1s[cb + r];
            b2v[n][r] = B2s[cb + r];
            w3v[n][r] = W3s[cb + r];
        }
        #pragma unroll
        for (int kt = 0; kt < 2; ++kt) {
            half8 h;
            #pragma unroll
            for (int r = 0; r < 8; ++r)
                h[r] = (_Float16)W1s[(kt * 32 + quad * 8 + r) * HH + j];
            w1f[kt][n] = h;
        }
        #pragma unroll
        for (int kt = 0; kt < 4; ++kt) {
            half8 h;
            #pragma unroll
            for (int r = 0; r < 8; ++r)
                h[r] = (_Float16)W2s[(kt * 32 + quad * 8 + r) * HH + j];
            w2f[kt][n] = h;
        }
    }

    // h1 write address pieces (transposed L1 output -> b64 stores)
    const int wc0  = (2 * w) * 2 + (quad >> 1);       // chunk idx, n=0
    const int wc1  = (2 * w + 1) * 2 + (quad >> 1);   // chunk idx, n=1
    const int wsub = (quad & 1) * 4;                  // half-offset in chunk

    #pragma unroll 1
    for (int t = bslot; t < NTILE; t += BPS) {
        // ---- z B-frags for this tile (pkrtz-packed f32->f16) ----
        half8 zf[2][2];   // [mt][kt]
        #pragma unroll
        for (int mt = 0; mt < 2; ++mt) {
            const float* p = emb + (size_t)(t * TM + mt * 16 + l15) * DD + quad * 8;
            #pragma unroll
            for (int kt = 0; kt < 2; ++kt) {
                floatx4 v0 = *(const floatx4*)(p + kt * 32);
                floatx4 v1 = *(const floatx4*)(p + kt * 32 + 4);
                union { half8 h; pk2 p2[4]; } u;
                u.p2[0] = __builtin_amdgcn_cvt_pkrtz(v0[0], v0[1]);
                u.p2[1] = __builtin_amdgcn_cvt_pkrtz(v0[2], v0[3]);
                u.p2[2] = __builtin_amdgcn_cvt_pkrtz(v1[0], v1[1]);
                u.p2[3] = __builtin_amdgcn_cvt_pkrtz(v1[2], v1[3]);
                zf[mt][kt] = u.h;
            }
        }

        // ---- layer 1 (transposed): D1T[col][item] ----
        floatx4 acc1[2][2];   // [mt][n]
        #pragma unroll
        for (int n = 0; n < 2; ++n)
            #pragma unroll
            for (int mt = 0; mt < 2; ++mt) acc1[mt][n] = b1v[n];
        #pragma unroll
        for (int kt = 0; kt < 2; ++kt)
            #pragma unroll
            for (int n = 0; n < 2; ++n)
                #pragma unroll
                for (int mt = 0; mt < 2; ++mt)
                    acc1[mt][n] = __builtin_amdgcn_mfma_f32_16x16x32_f16(
                        w1f[kt][n], zf[mt][kt], acc1[mt][n], 0, 0, 0);
        #pragma unroll
        for (int mt = 0; mt < 2; ++mt)
            #pragma unroll
            for (int n = 0; n < 2; ++n) {
                union { half4 h; pk2 p2[2]; } hu;
                hu.p2[0] = __builtin_amdgcn_cvt_pkrtz(
                    softplus_small(acc1[mt][n][0]), softplus_small(acc1[mt][n][1]));
                hu.p2[1] = __builtin_amdgcn_cvt_pkrtz(
                    softplus_small(acc1[mt][n][2]), softplus_small(acc1[mt][n][3]));
                int wc = n ? wc1 : wc0;
                *(half4*)(&h1s[(mt * 16 + l15) * HH + ((wc ^ l15) * 8) + wsub]) = hu.h;
            }
        __syncthreads();   // A: h1 complete before reads

        // ---- layer 2 + 3 partials (transposed) ----
        floatx4 acc2[2][2];
        #pragma unroll
        for (int n = 0; n < 2; ++n)
            #pragma unroll
            for (int mt = 0; mt < 2; ++mt) acc2[mt][n] = b2v[n];
        #pragma unroll
        for (int kt = 0; kt < 4; ++kt) {
            half8 af[2];
            #pragma unroll
            for (int mt = 0; mt < 2; ++mt)
                af[mt] = *(const half8*)(&h1s[(mt * 16 + l15) * HH +
                                              (((kt * 4 + quad) ^ l15) * 8)]);
            #pragma unroll
            for (int n = 0; n < 2; ++n)
                #pragma unroll
                for (int mt = 0; mt < 2; ++mt)
                    acc2[mt][n] = __builtin_amdgcn_mfma_f32_16x16x32_f16(
                        w2f[kt][n], af[mt], acc2[mt][n], 0, 0, 0);
        }
        #pragma unroll
        for (int mt = 0; mt < 2; ++mt) {
            float sv = 0.0f;
            #pragma unroll
            for (int n = 0; n < 2; ++n)
                #pragma unroll
                for (int r = 0; r < 4; ++r)
                    sv = fmaf(softplus_fast(acc2[mt][n][r]), w3v[n][r], sv);
            sv += __shfl_xor(sv, 16, 64);
            sv += __shfl_xor(sv, 32, 64);
            if (quad == 0)
                part[(mt * 16 + l15) * 4 + w] = sv;
        }
        __syncthreads();   // B: partials complete; also fences h1 reads

        if (tid < TM) {
            floatx4 pv = *(const floatx4*)(part + tid * 4);
            float s = (pv[0] + pv[1]) + (pv[2] + pv[3]);
            ma2[2 * (t * TM + tid) + is_exc] = softplus_safe(s) + EPSV;
        }
        // next-tile h1 writes are safe (all h1 reads precede barrier B);
        // next-tile part writes follow next barrier A, after these reads.
    }
}

// Tiny combine (r6-verified): out[w] = mu[it] + alpha[it] * spart[w].
__global__ __launch_bounds__(256) void combine_kernel(
    const int* __restrict__ items,
    const float* __restrict__ ma2,
    const float* __restrict__ spart,
    float* __restrict__ out)
{
    int w = blockIdx.x * 256 + threadIdx.x;   // NROW = 500*256 exactly
    int it = items[w];
    float2 g = *(const float2*)(ma2 + 2 * it);
    out[w] = fmaf(g.y, spart[w], g.x);
}

extern "C" void kernel_launch(void* const* d_in, const int* in_sizes, int n_in,
                              void* d_out, int out_size, void* d_ws, size_t ws_size,
                              hipStream_t stream)
{
    const int*   items = (const int*)  d_in[0];
    const float* qt    = (const float*)d_in[1];
    const float* hist  = (const float*)d_in[2];
    const float* emb   = (const float*)d_in[3];
    const float* W1    = (const float*)d_in[4];
    const float* b1    = (const float*)d_in[5];
    const float* W2    = (const float*)d_in[6];
    const float* b2    = (const float*)d_in[7];
    const float* W3    = (const float*)d_in[8];
    const float* V1    = (const float*)d_in[9];
    const float* c1    = (const float*)d_in[10];
    const float* V2    = (const float*)d_in[11];
    const float* c2    = (const float*)d_in[12];
    const float* V3    = (const float*)d_in[13];

    float* out   = (float*)d_out;
    float* ma2   = (float*)d_ws;                  // [NUM_ITEMS][2] mu,alpha
    float* spart = ma2 + 2 * NUM_ITEMS;           // [NROW]

    fused<<<NB_ALL, 256, 0, stream>>>(emb, W1, b1, W2, b2, W3,
                                      V1, c1, V2, c2, V3,
                                      qt, hist, ma2, spart);

    combine_kernel<<<NROW / 256, 256, 0, stream>>>(items, ma2, spart, out);
}

// Round 10
// 292.528 us; speedup vs baseline: 1.2774x; 1.2774x over previous
//
#include <hip/hip_runtime.h>
#include <math.h>

#define BB 256
#define CC 500
#define LL 200
#define DD 64
#define HH 128
#define NUM_ITEMS 100000
#define BETA 0.7f
#define EPSV 1e-8f

#define TM 32                        // items per tile (per mlp block)
#define NTILE (NUM_ITEMS / TM)       // 3125 exactly
#define BPS 1024                     // mlp blocks per weight set
#define NB_MLP (2 * BPS)             // 2048 mlp-role blocks
#define NB_HWK 512                   // persistent hawkes-role blocks
#define NB_ALL (NB_MLP + NB_HWK)     // 2560; bid%5==4 -> hawkes
#define NROW (BB * CC)               // 128000 rows; 250 rows per hawkes block

typedef _Float16 half8 __attribute__((ext_vector_type(8)));
typedef _Float16 half4 __attribute__((ext_vector_type(4)));
typedef __fp16   pk2   __attribute__((ext_vector_type(2)));  // cvt_pkrtz result type
typedef float floatx4 __attribute__((ext_vector_type(4)));

// Safe softplus (final scalar, any range)
__device__ __forceinline__ float softplus_safe(float x) {
    float t = __expf(-fabsf(x));
    return fmaxf(x, 0.0f) + __logf(1.0f + t);
}
// Layer-2 softplus: |x| bounded (~+-6 typical); exact fp32 form.
__device__ __forceinline__ float softplus_fast(float x) {
    return __logf(1.0f + __expf(x));
}
// Layer-1 softplus: preacts tiny (sigma~0.016). Taylor deg-4, err < f16 rounding.
__device__ __forceinline__ float softplus_small(float x) {
    float z = x * x;
    float p = fmaf(fmaf(-5.2083333e-3f, z, 0.125f), z, 0.69314718f);
    return fmaf(x, 0.5f, p);
}

// Duration-matched role-split fused kernel.
// ROUND-10 FIX: __launch_bounds__(256, 4) — r9's (256,8) capped the
// allocator at 32 arch-VGPRs, spilling the 48-VGPR weight set to scratch
// (WRITE_SIZE 157 MB, 236us). (256,4) is the bound under which this exact
// mlp body measured VGPR=64 / zero spill in r3/r6/r7.
//  - bid%5==4 (512 blocks): PERSISTENT hawkes role — each block owns a
//    contiguous 250-row window, ~62 rows/wave (~25-30us lifetime, matching
//    mlp block duration), so every CU keeps an HBM-streaming role and a
//    VALU/MFMA role resident for the whole kernel. Writes spart[r] only.
//  - Other 2048 blocks: the r3/r7-verified transposed-MFMA MLP body
//    (one weight set per block, 2 barriers/tile), writing ma2[2*item+set].
__global__ __launch_bounds__(256, 4) void fused(
    const float* __restrict__ emb,
    const float* __restrict__ W1, const float* __restrict__ b1,
    const float* __restrict__ W2, const float* __restrict__ b2,
    const float* __restrict__ W3,
    const float* __restrict__ V1, const float* __restrict__ c1,
    const float* __restrict__ V2, const float* __restrict__ c2,
    const float* __restrict__ V3,
    const float* __restrict__ qt,
    const float* __restrict__ hist,
    float* __restrict__ ma2,          // [NUM_ITEMS][2] interleaved mu,alpha
    float* __restrict__ spart)        // [NROW] scaled history sums
{
    __shared__ __align__(16) _Float16 h1s[TM * HH];   // 8192 B
    __shared__ __align__(16) float    part[TM * 4];   // 512 B
    int bid  = blockIdx.x;
    int tid  = threadIdx.x;
    int w    = tid >> 6, lane = tid & 63;

    if (bid % 5 == 4) {
        // ---------------- persistent hawkes role ----------------
        int hslot = bid / 5;                  // 0..NB_HWK-1
        int rend  = hslot * 250 + 250;        // 512*250 = 128000 exact
        #pragma unroll 2
        for (int r = hslot * 250 + w; r < rend; r += 4) {
            float q = qt[r / CC];
            float s = 0.0f;
            if (lane < LL / 4) {
                const floatx4* hp = (const floatx4*)(hist + (size_t)r * LL) + lane;
                floatx4 v = *hp;
                s  = (v[0] < q) ? __expf(BETA * v[0]) : 0.f;
                s += (v[1] < q) ? __expf(BETA * v[1]) : 0.f;
                s += (v[2] < q) ? __expf(BETA * v[2]) : 0.f;
                s += (v[3] < q) ? __expf(BETA * v[3]) : 0.f;
            }
            #pragma unroll
            for (int off = 1; off < 64; off <<= 1) s += __shfl_xor(s, off, 64);
            if (lane == 0)
                spart[r] = s * __expf(-BETA * q);
        }
        return;
    }

    // ---------------- mlp role (r3/r7-verified body) ----------------
    int mslot = bid - bid / 5;                // dense 0..NB_MLP-1 over bid%5!=4
    int quad = lane >> 4, l15 = lane & 15;

    int is_exc = mslot >= BPS;                // block-uniform
    int bslot  = mslot - (is_exc ? BPS : 0);  // 0..BPS-1

    const float* W1s = is_exc ? V1 : W1;
    const float* W2s = is_exc ? V2 : W2;
    const float* B1s = is_exc ? c1 : b1;
    const float* B2s = is_exc ? c2 : b2;
    const float* W3s = is_exc ? V3 : W3;

    // ---- stationary weights: wave w owns col groups 2w, 2w+1 ----
    half8 w1f[2][2];   // [kt][n]  (A-operand = W1^T slice)
    half8 w2f[4][2];   // [kt][n]  (A-operand = W2^T slice)
    floatx4 b1v[2], b2v[2], w3v[2];   // component r = col (2w+n)*16+quad*4+r
    #pragma unroll
    for (int n = 0; n < 2; ++n) {
        int j  = (2 * w + n) * 16 + l15;        // A-frag lane col
        int cb = (2 * w + n) * 16 + quad * 4;   // transposed-output col base
        #pragma unroll
        for (int r = 0; r < 4; ++r) {
            b1v[n][r] = B1s[cb + r];
            b2v[n][r] = B2s[cb + r];
            w3v[n][r] = W3s[cb + r];
        }
        #pragma unroll
        for (int kt = 0; kt < 2; ++kt) {
            half8 h;
            #pragma unroll
            for (int r = 0; r < 8; ++r)
                h[r] = (_Float16)W1s[(kt * 32 + quad * 8 + r) * HH + j];
            w1f[kt][n] = h;
        }
        #pragma unroll
        for (int kt = 0; kt < 4; ++kt) {
            half8 h;
            #pragma unroll
            for (int r = 0; r < 8; ++r)
                h[r] = (_Float16)W2s[(kt * 32 + quad * 8 + r) * HH + j];
            w2f[kt][n] = h;
        }
    }

    // h1 write address pieces (transposed L1 output -> b64 stores)
    const int wc0  = (2 * w) * 2 + (quad >> 1);       // chunk idx, n=0
    const int wc1  = (2 * w + 1) * 2 + (quad >> 1);   // chunk idx, n=1
    const int wsub = (quad & 1) * 4;                  // half-offset in chunk

    #pragma unroll 1
    for (int t = bslot; t < NTILE; t += BPS) {
        // ---- z B-frags for this tile (pkrtz-packed f32->f16) ----
        half8 zf[2][2];   // [mt][kt]
        #pragma unroll
        for (int mt = 0; mt < 2; ++mt) {
            const float* p = emb + (size_t)(t * TM + mt * 16 + l15) * DD + quad * 8;
            #pragma unroll
            for (int kt = 0; kt < 2; ++kt) {
                floatx4 v0 = *(const floatx4*)(p + kt * 32);
                floatx4 v1 = *(const floatx4*)(p + kt * 32 + 4);
                union { half8 h; pk2 p2[4]; } u;
                u.p2[0] = __builtin_amdgcn_cvt_pkrtz(v0[0], v0[1]);
                u.p2[1] = __builtin_amdgcn_cvt_pkrtz(v0[2], v0[3]);
                u.p2[2] = __builtin_amdgcn_cvt_pkrtz(v1[0], v1[1]);
                u.p2[3] = __builtin_amdgcn_cvt_pkrtz(v1[2], v1[3]);
                zf[mt][kt] = u.h;
            }
        }

        // ---- layer 1 (transposed): D1T[col][item] ----
        floatx4 acc1[2][2];   // [mt][n]
        #pragma unroll
        for (int n = 0; n < 2; ++n)
            #pragma unroll
            for (int mt = 0; mt < 2; ++mt) acc1[mt][n] = b1v[n];
        #pragma unroll
        for (int kt = 0; kt < 2; ++kt)
            #pragma unroll
            for (int n = 0; n < 2; ++n)
                #pragma unroll
                for (int mt = 0; mt < 2; ++mt)
                    acc1[mt][n] = __builtin_amdgcn_mfma_f32_16x16x32_f16(
                        w1f[kt][n], zf[mt][kt], acc1[mt][n], 0, 0, 0);
        #pragma unroll
        for (int mt = 0; mt < 2; ++mt)
            #pragma unroll
            for (int n = 0; n < 2; ++n) {
                union { half4 h; pk2 p2[2]; } hu;
                hu.p2[0] = __builtin_amdgcn_cvt_pkrtz(
                    softplus_small(acc1[mt][n][0]), softplus_small(acc1[mt][n][1]));
                hu.p2[1] = __builtin_amdgcn_cvt_pkrtz(
                    softplus_small(acc1[mt][n][2]), softplus_small(acc1[mt][n][3]));
                int wc = n ? wc1 : wc0;
                *(half4*)(&h1s[(mt * 16 + l15) * HH + ((wc ^ l15) * 8) + wsub]) = hu.h;
            }
        __syncthreads();   // A: h1 complete before reads

        // ---- layer 2 + 3 partials (transposed) ----
        floatx4 acc2[2][2];
        #pragma unroll
        for (int n = 0; n < 2; ++n)
            #pragma unroll
            for (int mt = 0; mt < 2; ++mt) acc2[mt][n] = b2v[n];
        #pragma unroll
        for (int kt = 0; kt < 4; ++kt) {
            half8 af[2];
            #pragma unroll
            for (int mt = 0; mt < 2; ++mt)
                af[mt] = *(const half8*)(&h1s[(mt * 16 + l15) * HH +
                                              (((kt * 4 + quad) ^ l15) * 8)]);
            #pragma unroll
            for (int n = 0; n < 2; ++n)
                #pragma unroll
                for (int mt = 0; mt < 2; ++mt)
                    acc2[mt][n] = __builtin_amdgcn_mfma_f32_16x16x32_f16(
                        w2f[kt][n], af[mt], acc2[mt][n], 0, 0, 0);
        }
        #pragma unroll
        for (int mt = 0; mt < 2; ++mt) {
            float sv = 0.0f;
            #pragma unroll
            for (int n = 0; n < 2; ++n)
                #pragma unroll
                for (int r = 0; r < 4; ++r)
                    sv = fmaf(softplus_fast(acc2[mt][n][r]), w3v[n][r], sv);
            sv += __shfl_xor(sv, 16, 64);
            sv += __shfl_xor(sv, 32, 64);
            if (quad == 0)
                part[(mt * 16 + l15) * 4 + w] = sv;
        }
        __syncthreads();   // B: partials complete; also fences h1 reads

        if (tid < TM) {
            floatx4 pv = *(const floatx4*)(part + tid * 4);
            float s = (pv[0] + pv[1]) + (pv[2] + pv[3]);
            ma2[2 * (t * TM + tid) + is_exc] = softplus_safe(s) + EPSV;
        }
        // next-tile h1 writes are safe (all h1 reads precede barrier B);
        // next-tile part writes follow next barrier A, after these reads.
    }
}

// Tiny combine (r6-verified): out[w] = mu[it] + alpha[it] * spart[w].
__global__ __launch_bounds__(256) void combine_kernel(
    const int* __restrict__ items,
    const float* __restrict__ ma2,
    const float* __restrict__ spart,
    float* __restrict__ out)
{
    int w = blockIdx.x * 256 + threadIdx.x;   // NROW = 500*256 exactly
    int it = items[w];
    float2 g = *(const float2*)(ma2 + 2 * it);
    out[w] = fmaf(g.y, spart[w], g.x);
}

extern "C" void kernel_launch(void* const* d_in, const int* in_sizes, int n_in,
                              void* d_out, int out_size, void* d_ws, size_t ws_size,
                              hipStream_t stream)
{
    const int*   items = (const int*)  d_in[0];
    const float* qt    = (const float*)d_in[1];
    const float* hist  = (const float*)d_in[2];
    const float* emb   = (const float*)d_in[3];
    const float* W1    = (const float*)d_in[4];
    const float* b1    = (const float*)d_in[5];
    const float* W2    = (const float*)d_in[6];
    const float* b2    = (const float*)d_in[7];
    const float* W3    = (const float*)d_in[8];
    const float* V1    = (const float*)d_in[9];
    const float* c1    = (const float*)d_in[10];
    const float* V2    = (const float*)d_in[11];
    const float* c2    = (const float*)d_in[12];
    const float* V3    = (const float*)d_in[13];

    float* out   = (float*)d_out;
    float* ma2   = (float*)d_ws;                  // [NUM_ITEMS][2] mu,alpha
    float* spart = ma2 + 2 * NUM_ITEMS;           // [NROW]

    fused<<<NB_ALL, 256, 0, stream>>>(emb, W1, b1, W2, b2, W3,
                                      V1, c1, V2, c2, V3,
                                      qt, hist, ma2, spart);

    combine_kernel<<<NROW / 256, 256, 0, stream>>>(items, ma2, spart, out);
}

// Round 11
// 231.955 us; speedup vs baseline: 1.6110x; 1.2611x over previous
//
#include <hip/hip_runtime.h>
#include <math.h>

#define BB 256
#define CC 500
#define LL 200
#define DD 64
#define HH 128
#define NUM_ITEMS 100000
#define BETA 0.7f
#define EPSV 1e-8f

#define TM 32                        // items per tile (per mlp block)
#define NTILE (NUM_ITEMS / TM)       // 3125 exactly
#define BPS 1024                     // mlp blocks per weight set
#define NROW (BB * CC)               // 128000 rows
#define NBH 8000                     // hawkes blocks: 32000 waves x 4 rows

typedef _Float16 half8 __attribute__((ext_vector_type(8)));
typedef _Float16 half4 __attribute__((ext_vector_type(4)));
typedef __fp16   pk2   __attribute__((ext_vector_type(2)));  // cvt_pkrtz result type
typedef float floatx4 __attribute__((ext_vector_type(4)));

// Safe softplus (final scalar, any range)
__device__ __forceinline__ float softplus_safe(float x) {
    float t = __expf(-fabsf(x));
    return fmaxf(x, 0.0f) + __logf(1.0f + t);
}
// Layer-2 softplus: |x| bounded (~+-6 typical); exact fp32 form.
__device__ __forceinline__ float softplus_fast(float x) {
    return __logf(1.0f + __expf(x));
}
// Layer-1 softplus: preacts tiny (sigma~0.016). Taylor deg-4, err < f16 rounding.
__device__ __forceinline__ float softplus_small(float x) {
    float z = x * x;
    float p = fmaf(fmaf(-5.2083333e-3f, z, 0.125f), z, 0.69314718f);
    return fmaf(x, 0.5f, p);
}

// Transposed-MFMA cooperative MLP (r3/r7-verified, best-measured structure).
// 4 waves / 256 threads, ONE weight set per block, 2 barriers/tile.
// mfma(W^T-frag, z-frag) -> output transposed: cols in regs, items on lanes.
// L1 epilogue = 4 ds_write_b64; L2 reduce = 16 fma + 2 shfl.
// Writes mu/alpha INTERLEAVED: ma2[2*item+set] (one float2 gather in hawkes).
// Blocks [0,BPS) -> mu set, [BPS,2*BPS) -> alpha set.
__global__ __launch_bounds__(256, 4) void mlp_mfma(
    const float* __restrict__ emb,
    const float* __restrict__ W1, const float* __restrict__ b1,
    const float* __restrict__ W2, const float* __restrict__ b2,
    const float* __restrict__ W3,
    const float* __restrict__ V1, const float* __restrict__ c1,
    const float* __restrict__ V2, const float* __restrict__ c2,
    const float* __restrict__ V3,
    float* __restrict__ ma2)          // [NUM_ITEMS][2] interleaved mu,alpha
{
    __shared__ __align__(16) _Float16 h1s[TM * HH];   // 8192 B
    __shared__ __align__(16) float    part[TM * 4];   // 512 B
    int tid  = threadIdx.x;
    int w    = tid >> 6, lane = tid & 63;
    int quad = lane >> 4, l15 = lane & 15;

    int is_exc = blockIdx.x >= BPS;                   // block-uniform
    int bslot  = blockIdx.x - (is_exc ? BPS : 0);     // 0..BPS-1

    const float* W1s = is_exc ? V1 : W1;
    const float* W2s = is_exc ? V2 : W2;
    const float* B1s = is_exc ? c1 : b1;
    const float* B2s = is_exc ? c2 : b2;
    const float* W3s = is_exc ? V3 : W3;

    // ---- stationary weights: wave w owns col groups 2w, 2w+1 ----
    half8 w1f[2][2];   // [kt][n]  (A-operand = W1^T slice)
    half8 w2f[4][2];   // [kt][n]  (A-operand = W2^T slice)
    floatx4 b1v[2], b2v[2], w3v[2];   // component r = col (2w+n)*16+quad*4+r
    #pragma unroll
    for (int n = 0; n < 2; ++n) {
        int j  = (2 * w + n) * 16 + l15;        // A-frag lane col
        int cb = (2 * w + n) * 16 + quad * 4;   // transposed-output col base
        #pragma unroll
        for (int r = 0; r < 4; ++r) {
            b1v[n][r] = B1s[cb + r];
            b2v[n][r] = B2s[cb + r];
            w3v[n][r] = W3s[cb + r];
        }
        #pragma unroll
        for (int kt = 0; kt < 2; ++kt) {
            half8 h;
            #pragma unroll
            for (int r = 0; r < 8; ++r)
                h[r] = (_Float16)W1s[(kt * 32 + quad * 8 + r) * HH + j];
            w1f[kt][n] = h;
        }
        #pragma unroll
        for (int kt = 0; kt < 4; ++kt) {
            half8 h;
            #pragma unroll
            for (int r = 0; r < 8; ++r)
                h[r] = (_Float16)W2s[(kt * 32 + quad * 8 + r) * HH + j];
            w2f[kt][n] = h;
        }
    }

    // h1 write address pieces (transposed L1 output -> b64 stores)
    const int wc0  = (2 * w) * 2 + (quad >> 1);       // chunk idx, n=0
    const int wc1  = (2 * w + 1) * 2 + (quad >> 1);   // chunk idx, n=1
    const int wsub = (quad & 1) * 4;                  // half-offset in chunk

    #pragma unroll 1
    for (int t = bslot; t < NTILE; t += BPS) {
        // ---- z B-frags for this tile (pkrtz-packed f32->f16) ----
        half8 zf[2][2];   // [mt][kt]
        #pragma unroll
        for (int mt = 0; mt < 2; ++mt) {
            const float* p = emb + (size_t)(t * TM + mt * 16 + l15) * DD + quad * 8;
            #pragma unroll
            for (int kt = 0; kt < 2; ++kt) {
                floatx4 v0 = *(const floatx4*)(p + kt * 32);
                floatx4 v1 = *(const floatx4*)(p + kt * 32 + 4);
                union { half8 h; pk2 p2[4]; } u;
                u.p2[0] = __builtin_amdgcn_cvt_pkrtz(v0[0], v0[1]);
                u.p2[1] = __builtin_amdgcn_cvt_pkrtz(v0[2], v0[3]);
                u.p2[2] = __builtin_amdgcn_cvt_pkrtz(v1[0], v1[1]);
                u.p2[3] = __builtin_amdgcn_cvt_pkrtz(v1[2], v1[3]);
                zf[mt][kt] = u.h;
            }
        }

        // ---- layer 1 (transposed): D1T[col][item] ----
        floatx4 acc1[2][2];   // [mt][n]
        #pragma unroll
        for (int n = 0; n < 2; ++n)
            #pragma unroll
            for (int mt = 0; mt < 2; ++mt) acc1[mt][n] = b1v[n];
        #pragma unroll
        for (int kt = 0; kt < 2; ++kt)
            #pragma unroll
            for (int n = 0; n < 2; ++n)
                #pragma unroll
                for (int mt = 0; mt < 2; ++mt)
                    acc1[mt][n] = __builtin_amdgcn_mfma_f32_16x16x32_f16(
                        w1f[kt][n], zf[mt][kt], acc1[mt][n], 0, 0, 0);
        #pragma unroll
        for (int mt = 0; mt < 2; ++mt)
            #pragma unroll
            for (int n = 0; n < 2; ++n) {
                union { half4 h; pk2 p2[2]; } hu;
                hu.p2[0] = __builtin_amdgcn_cvt_pkrtz(
                    softplus_small(acc1[mt][n][0]), softplus_small(acc1[mt][n][1]));
                hu.p2[1] = __builtin_amdgcn_cvt_pkrtz(
                    softplus_small(acc1[mt][n][2]), softplus_small(acc1[mt][n][3]));
                int wc = n ? wc1 : wc0;
                *(half4*)(&h1s[(mt * 16 + l15) * HH + ((wc ^ l15) * 8) + wsub]) = hu.h;
            }
        __syncthreads();   // A: h1 complete before reads

        // ---- layer 2 + 3 partials (transposed) ----
        floatx4 acc2[2][2];
        #pragma unroll
        for (int n = 0; n < 2; ++n)
            #pragma unroll
            for (int mt = 0; mt < 2; ++mt) acc2[mt][n] = b2v[n];
        #pragma unroll
        for (int kt = 0; kt < 4; ++kt) {
            half8 af[2];
            #pragma unroll
            for (int mt = 0; mt < 2; ++mt)
                af[mt] = *(const half8*)(&h1s[(mt * 16 + l15) * HH +
                                              (((kt * 4 + quad) ^ l15) * 8)]);
            #pragma unroll
            for (int n = 0; n < 2; ++n)
                #pragma unroll
                for (int mt = 0; mt < 2; ++mt)
                    acc2[mt][n] = __builtin_amdgcn_mfma_f32_16x16x32_f16(
                        w2f[kt][n], af[mt], acc2[mt][n], 0, 0, 0);
        }
        #pragma unroll
        for (int mt = 0; mt < 2; ++mt) {
            float sv = 0.0f;
            #pragma unroll
            for (int n = 0; n < 2; ++n)
                #pragma unroll
                for (int r = 0; r < 4; ++r)
                    sv = fmaf(softplus_fast(acc2[mt][n][r]), w3v[n][r], sv);
            sv += __shfl_xor(sv, 16, 64);
            sv += __shfl_xor(sv, 32, 64);
            if (quad == 0)
                part[(mt * 16 + l15) * 4 + w] = sv;
        }
        __syncthreads();   // B: partials complete; also fences h1 reads

        if (tid < TM) {
            floatx4 pv = *(const floatx4*)(part + tid * 4);
            float s = (pv[0] + pv[1]) + (pv[2] + pv[3]);
            ma2[2 * (t * TM + tid) + is_exc] = softplus_safe(s) + EPSV;
        }
        // next-tile h1 writes are safe (all h1 reads precede barrier B);
        // next-tile part writes follow next barrier A, after these reads.
    }
}

// Max-TLP/ILP Hawkes: 32000 waves, each owns 4 CONTIGUOUS rows.
// All 4 hist loads + 4 item ids + 4 ma2 gathers are issued UP FRONT
// (4 independent memory chains per wave; the dependent items->ma2 chain
// overlaps the exp/reduce compute, which only needs the hist values).
// Removes r7's loop-carried serial row-chain (7.8 rows/wave, 2 outstanding).
__global__ __launch_bounds__(256) void hawkes_kernel(
    const int* __restrict__ items,
    const float* __restrict__ qt,
    const float* __restrict__ hist,
    const float* __restrict__ ma2,
    float* __restrict__ out)
{
    int wv   = blockIdx.x * 4 + (threadIdx.x >> 6);  // 0..31999
    int lane = threadIdx.x & 63;
    int r0   = wv * 4;                               // rows r0..r0+3

    bool act = lane < LL / 4;
    int    it[4];
    float  q[4];
    floatx4 v[4];
    #pragma unroll
    for (int i = 0; i < 4; ++i) it[i] = items[r0 + i];
    #pragma unroll
    for (int i = 0; i < 4; ++i) q[i] = qt[(r0 + i) / CC];
    #pragma unroll
    for (int i = 0; i < 4; ++i)
        v[i] = act ? *((const floatx4*)(hist + (size_t)(r0 + i) * LL) + lane)
                   : (floatx4){0.f, 0.f, 0.f, 0.f};
    float2 g[4];
    #pragma unroll
    for (int i = 0; i < 4; ++i) g[i] = *(const float2*)(ma2 + 2 * it[i]);

    #pragma unroll
    for (int i = 0; i < 4; ++i) {
        float s = 0.0f;
        if (act) {
            s  = (v[i][0] < q[i]) ? __expf(BETA * v[i][0]) : 0.f;
            s += (v[i][1] < q[i]) ? __expf(BETA * v[i][1]) : 0.f;
            s += (v[i][2] < q[i]) ? __expf(BETA * v[i][2]) : 0.f;
            s += (v[i][3] < q[i]) ? __expf(BETA * v[i][3]) : 0.f;
        }
        #pragma unroll
        for (int off = 1; off < 64; off <<= 1) s += __shfl_xor(s, off, 64);
        if (lane == 0)
            out[r0 + i] = fmaf(g[i].y * __expf(-BETA * q[i]), s, g[i].x);
    }
}

extern "C" void kernel_launch(void* const* d_in, const int* in_sizes, int n_in,
                              void* d_out, int out_size, void* d_ws, size_t ws_size,
                              hipStream_t stream)
{
    const int*   items = (const int*)  d_in[0];
    const float* qt    = (const float*)d_in[1];
    const float* hist  = (const float*)d_in[2];
    const float* emb   = (const float*)d_in[3];
    const float* W1    = (const float*)d_in[4];
    const float* b1    = (const float*)d_in[5];
    const float* W2    = (const float*)d_in[6];
    const float* b2    = (const float*)d_in[7];
    const float* W3    = (const float*)d_in[8];
    const float* V1    = (const float*)d_in[9];
    const float* c1    = (const float*)d_in[10];
    const float* V2    = (const float*)d_in[11];
    const float* c2    = (const float*)d_in[12];
    const float* V3    = (const float*)d_in[13];

    float* out = (float*)d_out;
    float* ma2 = (float*)d_ws;                    // [NUM_ITEMS][2] mu,alpha

    // 2048 blocks x 256 threads; block = one 32-item tile, one weight set
    mlp_mfma<<<2 * BPS, 256, 0, stream>>>(emb, W1, b1, W2, b2, W3,
                                          V1, c1, V2, c2, V3, ma2);

    // 8000 blocks x 256 threads; wave = 4 contiguous rows, fully unrolled
    hawkes_kernel<<<NBH, 256, 0, stream>>>(items, qt, hist, ma2, out);
}

// Round 12
// 223.894 us; speedup vs baseline: 1.6690x; 1.0360x over previous
//
#include <hip/hip_runtime.h>
#include <math.h>

#define BB 256
#define CC 500
#define LL 200
#define DD 64
#define HH 128
#define NUM_ITEMS 100000
#define BETA 0.7f
#define EPSV 1e-8f

#define TM 32                        // items per tile (per mlp block)
#define NTILE (NUM_ITEMS / TM)       // 3125 exactly
#define BPS 1024                     // mlp blocks per weight set
#define NROW (BB * CC)               // 128000 rows
#define NBH 8000                     // hawkes blocks: 32000 waves x 4 rows

typedef _Float16 half8 __attribute__((ext_vector_type(8)));
typedef _Float16 half4 __attribute__((ext_vector_type(4)));
typedef __fp16   pk2   __attribute__((ext_vector_type(2)));  // cvt_pkrtz result type
typedef float floatx4 __attribute__((ext_vector_type(4)));

// Safe softplus (final scalar, any range)
__device__ __forceinline__ float softplus_safe(float x) {
    float t = __expf(-fabsf(x));
    return fmaxf(x, 0.0f) + __logf(1.0f + t);
}
// Layer-2 softplus: |x| bounded (~+-6 typical); exact fp32 form.
__device__ __forceinline__ float softplus_fast(float x) {
    return __logf(1.0f + __expf(x));
}
// Layer-1 softplus: preacts tiny (sigma~0.016). Taylor deg-4, err < f16 rounding.
__device__ __forceinline__ float softplus_small(float x) {
    float z = x * x;
    float p = fmaf(fmaf(-5.2083333e-3f, z, 0.125f), z, 0.69314718f);
    return fmaf(x, 0.5f, p);
}

// Transposed-MFMA cooperative MLP with LDS-staged, software-pipelined z.
// r3/r7-verified structure (4 waves / 256 threads, one weight set per block,
// 2 barriers/tile) + NEW: z(t+1) staged through a 4KB f16 LDS buffer:
//   - after barrier A: 256 threads issue 2 coalesced floatx4 loads (8KB/block,
//     non-redundant — previously all 4 waves loaded the SAME 8KB tile)
//   - after the L2 phase (global latency hidden under it): 4 pkrtz + one
//     swizzled ds_write_b128 into z_stage
//   - at loop-top: zf frags = 4 direct half8 ds_read_b128 (~120cy vs ~700cy
//     global), zero per-wave cvt.
// Swizzle: 16B chunk c stored at c ^ (item&7); read (kt*4+quad)^(l15&7).
// Hazards: z reads pre-A, z writes post-A (A fences WAR); writes pre-B,
// next-tile reads post-B (B fences RAW). Single buffer, no extra barriers.
__global__ __launch_bounds__(256, 4) void mlp_mfma(
    const float* __restrict__ emb,
    const float* __restrict__ W1, const float* __restrict__ b1,
    const float* __restrict__ W2, const float* __restrict__ b2,
    const float* __restrict__ W3,
    const float* __restrict__ V1, const float* __restrict__ c1,
    const float* __restrict__ V2, const float* __restrict__ c2,
    const float* __restrict__ V3,
    float* __restrict__ ma2)          // [NUM_ITEMS][2] interleaved mu,alpha
{
    __shared__ __align__(16) _Float16 h1s[TM * HH];     // 8192 B
    __shared__ __align__(16) _Float16 z_stage[TM * DD]; // 4096 B f16
    __shared__ __align__(16) float    part[TM * 4];     // 512 B
    int tid  = threadIdx.x;
    int w    = tid >> 6, lane = tid & 63;
    int quad = lane >> 4, l15 = lane & 15;

    int is_exc = blockIdx.x >= BPS;                   // block-uniform
    int bslot  = blockIdx.x - (is_exc ? BPS : 0);     // 0..BPS-1

    const float* W1s = is_exc ? V1 : W1;
    const float* W2s = is_exc ? V2 : W2;
    const float* B1s = is_exc ? c1 : b1;
    const float* B2s = is_exc ? c2 : b2;
    const float* W3s = is_exc ? V3 : W3;

    // staging thread mapping: item = tid>>3 (0..31), chunk c = tid&7 (8 f32)
    const int sitem = tid >> 3, schunk = tid & 7;
    const int soff  = sitem * DD + ((schunk ^ (sitem & 7)) * 8);  // f16 offset

    // ---- stationary weights: wave w owns col groups 2w, 2w+1 ----
    half8 w1f[2][2];   // [kt][n]  (A-operand = W1^T slice)
    half8 w2f[4][2];   // [kt][n]  (A-operand = W2^T slice)
    floatx4 b1v[2], b2v[2], w3v[2];   // component r = col (2w+n)*16+quad*4+r
    #pragma unroll
    for (int n = 0; n < 2; ++n) {
        int j  = (2 * w + n) * 16 + l15;        // A-frag lane col
        int cb = (2 * w + n) * 16 + quad * 4;   // transposed-output col base
        #pragma unroll
        for (int r = 0; r < 4; ++r) {
            b1v[n][r] = B1s[cb + r];
            b2v[n][r] = B2s[cb + r];
            w3v[n][r] = W3s[cb + r];
        }
        #pragma unroll
        for (int kt = 0; kt < 2; ++kt) {
            half8 h;
            #pragma unroll
            for (int r = 0; r < 8; ++r)
                h[r] = (_Float16)W1s[(kt * 32 + quad * 8 + r) * HH + j];
            w1f[kt][n] = h;
        }
        #pragma unroll
        for (int kt = 0; kt < 4; ++kt) {
            half8 h;
            #pragma unroll
            for (int r = 0; r < 8; ++r)
                h[r] = (_Float16)W2s[(kt * 32 + quad * 8 + r) * HH + j];
            w2f[kt][n] = h;
        }
    }

    // h1 write address pieces (transposed L1 output -> b64 stores)
    const int wc0  = (2 * w) * 2 + (quad >> 1);       // chunk idx, n=0
    const int wc1  = (2 * w + 1) * 2 + (quad >> 1);   // chunk idx, n=1
    const int wsub = (quad & 1) * 4;                  // half-offset in chunk

    // ---- prologue: stage z(bslot) ----
    {
        const float* ps = emb + (size_t)(bslot * TM + sitem) * DD + schunk * 8;
        floatx4 s0 = *(const floatx4*)ps;
        floatx4 s1 = *(const floatx4*)(ps + 4);
        union { half8 h; pk2 p2[4]; } u;
        u.p2[0] = __builtin_amdgcn_cvt_pkrtz(s0[0], s0[1]);
        u.p2[1] = __builtin_amdgcn_cvt_pkrtz(s0[2], s0[3]);
        u.p2[2] = __builtin_amdgcn_cvt_pkrtz(s1[0], s1[1]);
        u.p2[3] = __builtin_amdgcn_cvt_pkrtz(s1[2], s1[3]);
        *(half8*)(&z_stage[soff]) = u.h;
    }
    __syncthreads();

    #pragma unroll 1
    for (int t = bslot; t < NTILE; t += BPS) {
        bool more = (t + BPS) < NTILE;

        // ---- z B-frags: direct half8 reads from swizzled z_stage ----
        half8 zf[2][2];   // [mt][kt]
        #pragma unroll
        for (int mt = 0; mt < 2; ++mt)
            #pragma unroll
            for (int kt = 0; kt < 2; ++kt)
                zf[mt][kt] = *(const half8*)(&z_stage[(mt * 16 + l15) * DD +
                                             (((kt * 4 + quad) ^ (l15 & 7)) * 8)]);

        // ---- layer 1 (transposed): D1T[col][item] ----
        floatx4 acc1[2][2];   // [mt][n]
        #pragma unroll
        for (int n = 0; n < 2; ++n)
            #pragma unroll
            for (int mt = 0; mt < 2; ++mt) acc1[mt][n] = b1v[n];
        #pragma unroll
        for (int kt = 0; kt < 2; ++kt)
            #pragma unroll
            for (int n = 0; n < 2; ++n)
                #pragma unroll
                for (int mt = 0; mt < 2; ++mt)
                    acc1[mt][n] = __builtin_amdgcn_mfma_f32_16x16x32_f16(
                        w1f[kt][n], zf[mt][kt], acc1[mt][n], 0, 0, 0);
        #pragma unroll
        for (int mt = 0; mt < 2; ++mt)
            #pragma unroll
            for (int n = 0; n < 2; ++n) {
                union { half4 h; pk2 p2[2]; } hu;
                hu.p2[0] = __builtin_amdgcn_cvt_pkrtz(
                    softplus_small(acc1[mt][n][0]), softplus_small(acc1[mt][n][1]));
                hu.p2[1] = __builtin_amdgcn_cvt_pkrtz(
                    softplus_small(acc1[mt][n][2]), softplus_small(acc1[mt][n][3]));
                int wc = n ? wc1 : wc0;
                *(half4*)(&h1s[(mt * 16 + l15) * HH + ((wc ^ l15) * 8) + wsub]) = hu.h;
            }
        __syncthreads();   // A: h1 complete; z_stage reads complete (WAR fence)

        // ---- issue z(t+1) global loads (latency hides under L2 phase) ----
        floatx4 s0 = {0.f, 0.f, 0.f, 0.f}, s1 = {0.f, 0.f, 0.f, 0.f};
        {
            const float* ps = emb + (size_t)((t + BPS) * TM + sitem) * DD + schunk * 8;
            if (more) {
                s0 = *(const floatx4*)ps;
                s1 = *(const floatx4*)(ps + 4);
            }
        }

        // ---- layer 2 + 3 partials (transposed) ----
        floatx4 acc2[2][2];
        #pragma unroll
        for (int n = 0; n < 2; ++n)
            #pragma unroll
            for (int mt = 0; mt < 2; ++mt) acc2[mt][n] = b2v[n];
        #pragma unroll
        for (int kt = 0; kt < 4; ++kt) {
            half8 af[2];
            #pragma unroll
            for (int mt = 0; mt < 2; ++mt)
                af[mt] = *(const half8*)(&h1s[(mt * 16 + l15) * HH +
                                              (((kt * 4 + quad) ^ l15) * 8)]);
            #pragma unroll
            for (int n = 0; n < 2; ++n)
                #pragma unroll
                for (int mt = 0; mt < 2; ++mt)
                    acc2[mt][n] = __builtin_amdgcn_mfma_f32_16x16x32_f16(
                        w2f[kt][n], af[mt], acc2[mt][n], 0, 0, 0);
        }
        #pragma unroll
        for (int mt = 0; mt < 2; ++mt) {
            float sv = 0.0f;
            #pragma unroll
            for (int n = 0; n < 2; ++n)
                #pragma unroll
                for (int r = 0; r < 4; ++r)
                    sv = fmaf(softplus_fast(acc2[mt][n][r]), w3v[n][r], sv);
            sv += __shfl_xor(sv, 16, 64);
            sv += __shfl_xor(sv, 32, 64);
            if (quad == 0)
                part[(mt * 16 + l15) * 4 + w] = sv;
        }

        // ---- write staged z(t+1) into z_stage (RAW fenced by barrier B) ----
        if (more) {
            union { half8 h; pk2 p2[4]; } u;
            u.p2[0] = __builtin_amdgcn_cvt_pkrtz(s0[0], s0[1]);
            u.p2[1] = __builtin_amdgcn_cvt_pkrtz(s0[2], s0[3]);
            u.p2[2] = __builtin_amdgcn_cvt_pkrtz(s1[0], s1[1]);
            u.p2[3] = __builtin_amdgcn_cvt_pkrtz(s1[2], s1[3]);
            *(half8*)(&z_stage[soff]) = u.h;
        }
        __syncthreads();   // B: partials + z_stage complete; fences h1 reads

        if (tid < TM) {
            floatx4 pv = *(const floatx4*)(part + tid * 4);
            float s = (pv[0] + pv[1]) + (pv[2] + pv[3]);
            ma2[2 * (t * TM + tid) + is_exc] = softplus_safe(s) + EPSV;
        }
        // next-tile h1/z_stage writes are safe: all reads precede barrier B,
        // and next-tile writes follow next barrier A.
    }
}

// Max-TLP/ILP Hawkes (r11-verified): 32000 waves, each owns 4 CONTIGUOUS
// rows; all 4 hist loads + item ids + ma2 gathers issued UP FRONT.
__global__ __launch_bounds__(256) void hawkes_kernel(
    const int* __restrict__ items,
    const float* __restrict__ qt,
    const float* __restrict__ hist,
    const float* __restrict__ ma2,
    float* __restrict__ out)
{
    int wv   = blockIdx.x * 4 + (threadIdx.x >> 6);  // 0..31999
    int lane = threadIdx.x & 63;
    int r0   = wv * 4;                               // rows r0..r0+3

    bool act = lane < LL / 4;
    int    it[4];
    float  q[4];
    floatx4 v[4];
    #pragma unroll
    for (int i = 0; i < 4; ++i) it[i] = items[r0 + i];
    #pragma unroll
    for (int i = 0; i < 4; ++i) q[i] = qt[(r0 + i) / CC];
    #pragma unroll
    for (int i = 0; i < 4; ++i)
        v[i] = act ? *((const floatx4*)(hist + (size_t)(r0 + i) * LL) + lane)
                   : (floatx4){0.f, 0.f, 0.f, 0.f};
    float2 g[4];
    #pragma unroll
    for (int i = 0; i < 4; ++i) g[i] = *(const float2*)(ma2 + 2 * it[i]);

    #pragma unroll
    for (int i = 0; i < 4; ++i) {
        float s = 0.0f;
        if (act) {
            s  = (v[i][0] < q[i]) ? __expf(BETA * v[i][0]) : 0.f;
            s += (v[i][1] < q[i]) ? __expf(BETA * v[i][1]) : 0.f;
            s += (v[i][2] < q[i]) ? __expf(BETA * v[i][2]) : 0.f;
            s += (v[i][3] < q[i]) ? __expf(BETA * v[i][3]) : 0.f;
        }
        #pragma unroll
        for (int off = 1; off < 64; off <<= 1) s += __shfl_xor(s, off, 64);
        if (lane == 0)
            out[r0 + i] = fmaf(g[i].y * __expf(-BETA * q[i]), s, g[i].x);
    }
}

extern "C" void kernel_launch(void* const* d_in, const int* in_sizes, int n_in,
                              void* d_out, int out_size, void* d_ws, size_t ws_size,
                              hipStream_t stream)
{
    const int*   items = (const int*)  d_in[0];
    const float* qt    = (const float*)d_in[1];
    const float* hist  = (const float*)d_in[2];
    const float* emb   = (const float*)d_in[3];
    const float* W1    = (const float*)d_in[4];
    const float* b1    = (const float*)d_in[5];
    const float* W2    = (const float*)d_in[6];
    const float* b2    = (const float*)d_in[7];
    const float* W3    = (const float*)d_in[8];
    const float* V1    = (const float*)d_in[9];
    const float* c1    = (const float*)d_in[10];
    const float* V2    = (const float*)d_in[11];
    const float* c2    = (const float*)d_in[12];
    const float* V3    = (const float*)d_in[13];

    float* out = (float*)d_out;
    float* ma2 = (float*)d_ws;                    // [NUM_ITEMS][2] mu,alpha

    // 2048 blocks x 256 threads; block = one 32-item tile, one weight set
    mlp_mfma<<<2 * BPS, 256, 0, stream>>>(emb, W1, b1, W2, b2, W3,
                                          V1, c1, V2, c2, V3, ma2);

    // 8000 blocks x 256 threads; wave = 4 contiguous rows, fully unrolled
    hawkes_kernel<<<NBH, 256, 0, stream>>>(items, qt, hist, ma2, out);
}